// Round 1
// baseline (120.086 us; speedup 1.0000x reference)
//
#include <hip/hip_runtime.h>

// Static shapes from setup_inputs(): B=16, T=512, D=384, F=max_len=4096.
#define BB 16
#define TT 512
#define FF 4096
#define DD 384
#define DD4 (DD / 4)        // 96 float4 per frame
#define FPB 8               // frames per block in gather: 8*96 = 768 = 3*256

// Kernel 1: one block per batch. Inclusive scan of durations (LDS,
// Hillis-Steele), then scatter phoneme index t into frame_idx[cum-d .. cum).
// Frames past the total stay -1 (zero-fill in gather).
__global__ __launch_bounds__(TT) void build_idx_kernel(
    const int* __restrict__ dur, int* __restrict__ fidx) {
    const int b = blockIdx.x;
    const int t = threadIdx.x;
    int* fb = fidx + b * FF;

    // init frame index to -1 (ws is poisoned 0xAA each call)
#pragma unroll
    for (int k = 0; k < FF / TT; ++k) fb[k * TT + t] = -1;

    __shared__ int s[TT];
    const int d = dur[b * TT + t];
    s[t] = d;
    __syncthreads();
#pragma unroll
    for (int off = 1; off < TT; off <<= 1) {
        int v = (t >= off) ? s[t - off] : 0;
        __syncthreads();
        s[t] += v;
        __syncthreads();
    }
    const int cum = s[t];            // inclusive cumsum
    const int start = cum - d;
    const int end = cum < FF ? cum : FF;   // max total = 512*7 = 3584 < 4096
    for (int f = start; f < end; ++f) fb[f] = t;
}

// Kernel 2: each block copies 8 frames (8 * 384 floats = 768 float4).
// Coalesced float4 stores; x rows come from L1/L2 (x is 12.6 MB total).
__global__ __launch_bounds__(256) void gather_kernel(
    const float4* __restrict__ x, const int* __restrict__ fidx,
    float4* __restrict__ out) {
    const int tilesPerBatch = FF / FPB;  // 512
    const int bid = blockIdx.x;
    const int b = bid / tilesPerBatch;
    const int tile = bid - b * tilesPerBatch;
    const int f0 = tile * FPB;

    __shared__ int idx8[FPB];
    if (threadIdx.x < FPB)
        idx8[threadIdx.x] = fidx[b * FF + f0 + threadIdx.x];
    __syncthreads();

    const float4* xb = x + (size_t)b * TT * DD4;
    float4* ob = out + ((size_t)b * FF + f0) * DD4;

#pragma unroll
    for (int k = 0; k < 3; ++k) {
        const int pos = k * 256 + (int)threadIdx.x;   // 0..767
        const int fl = pos / DD4;                     // frame within tile
        const int c = pos - fl * DD4;                 // float4 column
        const int idx = idx8[fl];
        float4 v;
        if (idx >= 0) {
            v = xb[(size_t)idx * DD4 + c];
        } else {
            v = make_float4(0.f, 0.f, 0.f, 0.f);
        }
        ob[pos] = v;
    }
}

extern "C" void kernel_launch(void* const* d_in, const int* in_sizes, int n_in,
                              void* d_out, int out_size, void* d_ws, size_t ws_size,
                              hipStream_t stream) {
    const float* x = (const float*)d_in[0];
    const int* dur = (const int*)d_in[1];   // int32 on device (JAX x64 off)
    int* fidx = (int*)d_ws;                 // B*F ints = 256 KB scratch

    build_idx_kernel<<<BB, TT, 0, stream>>>(dur, fidx);
    gather_kernel<<<BB * (FF / FPB), 256, 0, stream>>>(
        (const float4*)x, fidx, (float4*)d_out);
}